// Round 1
// 444.754 us; speedup vs baseline: 1.0573x; 1.0573x over previous
//
#include <hip/hip_runtime.h>
#include <stdint.h>

// WhiteboxGATBlock: N=100000, D=256, K=4, R=16, E=1700000 (1.6M rand + 100k self-loops)
// All tensors fp32. Algebra:
//   M = 0.5*(D - (D^T D) D), A = I + M
//   H = 0.5*Z + 0.5*V@W  (V = head-weighted normalized attention agg, W[j][d]=U[j>>4][d][j&15])
//   out = relu(H@A - 0.05) = relu( Z@(0.5A) + V@(0.5*W@A) - 0.05 )
// => fused MFMA GEMM K=320 over [Zb | Vb] @ Bt. ZU for attention logits is ALSO an MFMA
//    GEMM (bf16 in, fp32 acc).
// Edge softmax: shift-invariant; self-loop guarantees denom > 0; fp32-safe without segmax.
// CSR build: deterministic two-level partition (bucket = dst>>8), LDS cursors only.
//
// R1 change (latency-bound k_out/k_zumm, MfmaUtil 7%, occ 27%, HBM 19%):
//   - k_out: LDS-stage Zb (32KB) + Vb (8KB) tiles once per block, XOR-swizzled
//     (chunk_col ^= row&7) so ds_read_b128 fragment reads are conflict-free
//     (512B row stride = all-rows-bank-0 otherwise). All 4 waves share the tile.
//   - k_zumm: same staging, fused with the Z->bf16 cast (k_cast deleted): staging
//     loop reads Z fp32, converts, ds_writes swizzled LDS AND stores linear Zb.

typedef unsigned short u16;
typedef unsigned int u32;
typedef __attribute__((ext_vector_type(8))) short bf16x8;   // 4 VGPRs, MFMA A/B frag
typedef __attribute__((ext_vector_type(4))) float f32x4;    // MFMA C/D frag

#define PB 256   // partition blocks

__device__ __forceinline__ u16 f2bf(float f) {
    u32 u = __float_as_uint(f);
    u32 r = u + 0x7fffu + ((u >> 16) & 1u);   // RNE
    return (u16)(r >> 16);
}

// ---------- prep: G = D^T D (256x256) ----------
__global__ void k_prep1(const float* __restrict__ D, float* __restrict__ G) {
    int i = blockIdx.x, j = threadIdx.x;
    float acc = 0.f;
    for (int d = 0; d < 256; ++d)
        acc += D[d * 256 + i] * D[d * 256 + j];
    G[i * 256 + j] = acc;
}

// ---------- prep: A = I + 0.5*(D - G@D)  (fp32) ----------
__global__ void k_prep2(const float* __restrict__ D, const float* __restrict__ G,
                        float* __restrict__ A) {
    int t = blockIdx.x, j = threadIdx.x;   // row t, col j
    float acc = 0.f;
    for (int u = 0; u < 256; ++u)
        acc += G[t * 256 + u] * D[u * 256 + j];
    A[t * 256 + j] = 0.5f * (D[t * 256 + j] - acc) + (t == j ? 1.f : 0.f);
}

// ---------- prep: Bt[c][k] = bf16(0.5*A[k][c]) for k<256 (B stored [col][k], 320-stride) ----------
__global__ void k_prep3(const float* __restrict__ A, u16* __restrict__ Bt) {
    int c = blockIdx.x, k = threadIdx.x;
    Bt[c * 320 + k] = f2bf(0.5f * A[k * 256 + c]);
}

// ---------- prep: Bt[c][256+j] = bf16(0.5 * sum_d W[j][d]*A[d][c]) ----------
__global__ void k_prep4(const float* __restrict__ U, const float* __restrict__ A,
                        u16* __restrict__ Bt) {
    int j = blockIdx.x, c = threadIdx.x;
    int k = j >> 4, r = j & 15;
    float acc = 0.f;
    for (int d = 0; d < 256; ++d)
        acc += U[k * 4096 + d * 16 + r] * A[d * 256 + c];
    Bt[c * 320 + 256 + j] = f2bf(0.5f * acc);
}

// ---------- prep: U2t[j][d] = bf16(U[j>>4][d][j&15])  (64x256, B-operand for k_zumm) ----------
__global__ void k_prep5(const float* __restrict__ U, u16* __restrict__ U2t) {
    int j = blockIdx.x, d = threadIdx.x;
    U2t[j * 256 + d] = f2bf(U[(j >> 4) * 4096 + d * 16 + (j & 15)]);
}

// ---------- partition pass 1: per-block histogram over coarse buckets ----------
__global__ __launch_bounds__(256) void k_cnt1(const int* __restrict__ ei,
                                              int* __restrict__ cnt2, int E, int nbuck) {
    __shared__ int h[512];
    int t = threadIdx.x, b = blockIdx.x;
    for (int i = t; i < nbuck; i += 256) h[i] = 0;
    __syncthreads();
    int per = (E + PB - 1) / PB;
    int lo = b * per;
    int hi = lo + per; if (hi > E) hi = E;
    for (int e = lo + t; e < hi; e += 256)
        atomicAdd(&h[ei[E + e] >> 8], 1);
    __syncthreads();
    for (int i = t; i < nbuck; i += 256)
        cnt2[b * nbuck + i] = h[i];
}

// ---------- partition pass 2a: per-bucket scan across blocks ----------
__global__ __launch_bounds__(256) void k_cscan1(const int* __restrict__ cnt2,
                                                int* __restrict__ pre2,
                                                int* __restrict__ tot, int nbuck) {
    __shared__ int s[256];
    int t = threadIdx.x, b = blockIdx.x;
    int v = cnt2[t * nbuck + b];
    s[t] = v;
    __syncthreads();
    for (int o = 1; o < 256; o <<= 1) {
        int x = (t >= o) ? s[t - o] : 0;
        __syncthreads();
        s[t] += x;
        __syncthreads();
    }
    pre2[t * nbuck + b] = s[t] - v;
    if (t == 255) tot[b] = s[255];
}

// ---------- partition pass 2b: scan bucket totals ----------
__global__ __launch_bounds__(512) void k_cscan2(const int* __restrict__ tot,
                                                int* __restrict__ bbase, int nbuck) {
    __shared__ int s[512];
    int t = threadIdx.x;
    int v = (t < nbuck) ? tot[t] : 0;
    s[t] = v;
    __syncthreads();
    for (int o = 1; o < 512; o <<= 1) {
        int x = (t >= o) ? s[t - o] : 0;
        __syncthreads();
        s[t] += x;
        __syncthreads();
    }
    if (t < nbuck) bbase[t] = s[t] - v;
}

// ---------- partition pass 3: place packed (src<<8 | dst&255) into coarse buckets ----------
__global__ __launch_bounds__(256) void k_place(const int* __restrict__ ei,
                                               const int* __restrict__ pre2,
                                               const int* __restrict__ bbase,
                                               int* __restrict__ part, int E, int nbuck) {
    __shared__ int baseS[512];
    __shared__ int cur[512];
    int t = threadIdx.x, b = blockIdx.x;
    for (int i = t; i < nbuck; i += 256) {
        baseS[i] = bbase[i] + pre2[b * nbuck + i];
        cur[i] = 0;
    }
    __syncthreads();
    int per = (E + PB - 1) / PB;
    int lo = b * per;
    int hi = lo + per; if (hi > E) hi = E;
    for (int e = lo + t; e < hi; e += 256) {
        int s = ei[e];
        int d = ei[E + e];
        int bk = d >> 8;
        int r = atomicAdd(&cur[bk], 1);          // LDS atomic
        part[baseS[bk] + r] = (s << 8) | (d & 255);
    }
}

// ---------- partition pass 4: within-bucket CSR finalize (off/cnt/esrc), LDS cursors ----------
__global__ __launch_bounds__(256) void k_bucket(const int* __restrict__ part,
                                                const int* __restrict__ tot,
                                                const int* __restrict__ bbase,
                                                int* __restrict__ off,
                                                int* __restrict__ cnt,
                                                int* __restrict__ esrc, int n) {
    __shared__ int ncnt[256], excl[256], cur[256], sc[256];
    int t = threadIdx.x, b = blockIdx.x;
    ncnt[t] = 0;
    cur[t] = 0;
    __syncthreads();
    int base = bbase[b], m = tot[b];
    for (int i = t; i < m; i += 256)
        atomicAdd(&ncnt[part[base + i] & 255], 1);
    __syncthreads();
    int v = ncnt[t];
    sc[t] = v;
    __syncthreads();
    for (int o = 1; o < 256; o <<= 1) {
        int x = (t >= o) ? sc[t - o] : 0;
        __syncthreads();
        sc[t] += x;
        __syncthreads();
    }
    excl[t] = sc[t] - v;
    int node = b * 256 + t;
    if (node < n) {
        off[node] = base + excl[t];
        cnt[node] = v;
    }
    __syncthreads();
    for (int i = t; i < m; i += 256) {
        int pk = part[base + i];
        int j = pk & 255;
        int r = atomicAdd(&cur[j], 1);           // LDS atomic
        esrc[base + excl[j] + r] = pk >> 8;
    }
}

// ---------- ZU = bf16(Z) @ U2t^T via MFMA (fp32 out), fused cast (emits Zb) ----------
// block = 4 waves over a shared 64-row tile; wave w computes rows w*16..w*16+15.
// Staging: read Z fp32, RNE->bf16, ds_write XOR-swizzled LDS tile + linear Zb global.
__global__ __launch_bounds__(256) void k_zumm(const float* __restrict__ Z,
                                              const u16* __restrict__ U2t,
                                              float* __restrict__ ZU,
                                              u16* __restrict__ Zb, int n) {
    __shared__ __align__(16) u16 sA[64 * 256];   // 32 KB, rows 512B, swizzled
    const int t = threadIdx.x;
    const int w = t >> 6;
    const int lane = t & 63;
    const int m16 = lane & 15;
    const int quad = lane >> 4;
    const int nb = blockIdx.x * 64;

    // stage + cast: 64 rows x 32 chunks(16B bf16 = 8 fp32) = 2048 chunks, 8 iters
#pragma unroll
    for (int i = 0; i < 8; ++i) {
        int c = i * 256 + t;
        int row = c >> 5, col = c & 31;
        int grow = nb + row;
        int gr = grow < n ? grow : n - 1;
        const float4* zp = reinterpret_cast<const float4*>(Z + (size_t)gr * 256 + col * 8);
        float4 a = zp[0], b = zp[1];
        uint4 pk;
        pk.x = (u32)f2bf(a.x) | ((u32)f2bf(a.y) << 16);
        pk.y = (u32)f2bf(a.z) | ((u32)f2bf(a.w) << 16);
        pk.z = (u32)f2bf(b.x) | ((u32)f2bf(b.y) << 16);
        pk.w = (u32)f2bf(b.z) | ((u32)f2bf(b.w) << 16);
        // swizzle: chunk col ^= row&7  (spreads the 512B-stride column across banks)
        *reinterpret_cast<uint4*>((char*)sA + row * 512 + ((col ^ (row & 7)) << 4)) = pk;
        if (grow < n)
            *reinterpret_cast<uint4*>(Zb + (size_t)grow * 256 + col * 8) = pk;
    }
    __syncthreads();

    f32x4 acc[4];
#pragma unroll
    for (int nt = 0; nt < 4; ++nt) acc[nt] = (f32x4){0.f, 0.f, 0.f, 0.f};

    const int arow = w * 16 + m16;
    const u32 abase = (u32)arow * 512;
    const u32 asw = (u32)(m16 & 7) << 4;

    for (int ks = 0; ks < 8; ++ks) {
        bf16x8 a = *reinterpret_cast<const bf16x8*>(
            (char*)sA + abase + (((u32)(ks * 64 + quad * 16)) ^ asw));
#pragma unroll
        for (int nt = 0; nt < 4; ++nt) {
            bf16x8 b = *reinterpret_cast<const bf16x8*>(
                U2t + (size_t)(nt * 16 + m16) * 256 + ks * 32 + quad * 8);
            acc[nt] = __builtin_amdgcn_mfma_f32_16x16x32_bf16(a, b, acc[nt], 0, 0, 0);
        }
    }
    // D: row=quad*4+r (node), col=m16 (output within nt tile)
#pragma unroll
    for (int r = 0; r < 4; ++r) {
        int node = nb + w * 16 + quad * 4 + r;
        if (node < n) {
#pragma unroll
            for (int nt = 0; nt < 4; ++nt)
                ZU[(size_t)node * 64 + nt * 16 + m16] = acc[nt][r];
        }
    }
}

// ---------- per-node aggregation: 1 wave/node, 4 edges in flight; emits bf16 V ----------
// lane = g*16+q: group g handles edge c0+g, lane q holds dims 4q..4q+3 (float4)
__global__ __launch_bounds__(256) void k_agg(const float* __restrict__ ZU,
                                             const int* __restrict__ esrc,
                                             const int* __restrict__ off,
                                             const int* __restrict__ cnt,
                                             const float* __restrict__ hwp,
                                             u16* __restrict__ Vb, int n) {
    int node = blockIdx.x * 4 + (threadIdx.x >> 6);
    int lane = threadIdx.x & 63;
    if (node >= n) return;
    const int q = lane & 15;
    const int g = lane >> 4;
    float4 zd4 = *reinterpret_cast<const float4*>(&ZU[(size_t)node * 64 + q * 4]);
    int base = off[node];
    int deg = cnt[node];

    float ax = 0.f, ay = 0.f, az = 0.f, aw = 0.f, ssum = 0.f;
    for (int c0 = 0; c0 < deg; c0 += 4) {
        int e = c0 + g;
        bool valid = e < deg;
        int s = valid ? esrc[base + e] : 0;
        float4 zs4 = *reinterpret_cast<const float4*>(&ZU[(size_t)s * 64 + q * 4]);
        float p = zs4.x * zd4.x + zs4.y * zd4.y + zs4.z * zd4.z + zs4.w * zd4.w;
        p += __shfl_xor(p, 1);
        p += __shfl_xor(p, 2);              // head dot across 4-lane subgroup
        float ew = valid ? __expf(p * 0.25f) : 0.f;   // / sqrt(R)=4
        ax += ew * zs4.x; ay += ew * zs4.y;
        az += ew * zs4.z; aw += ew * zs4.w;
        ssum += ew;
    }
    ax += __shfl_xor(ax, 16); ax += __shfl_xor(ax, 32);
    ay += __shfl_xor(ay, 16); ay += __shfl_xor(ay, 32);
    az += __shfl_xor(az, 16); az += __shfl_xor(az, 32);
    aw += __shfl_xor(aw, 16); aw += __shfl_xor(aw, 32);
    ssum += __shfl_xor(ssum, 16); ssum += __shfl_xor(ssum, 32);

    if (g == 0) {
        float h0 = hwp[0], h1 = hwp[1], h2 = hwp[2], h3 = hwp[3];
        float mx = fmaxf(fmaxf(h0, h1), fmaxf(h2, h3));
        float e0 = __expf(h0 - mx), e1 = __expf(h1 - mx),
              e2 = __expf(h2 - mx), e3 = __expf(h3 - mx);
        float es = e0 + e1 + e2 + e3;
        int hd = q >> 2;
        float wk = (hd == 0 ? e0 : hd == 1 ? e1 : hd == 2 ? e2 : e3) / es;
        float inv = wk / ssum;
        uint2 pk;
        pk.x = (u32)f2bf(ax * inv) | ((u32)f2bf(ay * inv) << 16);
        pk.y = (u32)f2bf(az * inv) | ((u32)f2bf(aw * inv) << 16);
        *reinterpret_cast<uint2*>(&Vb[(size_t)node * 64 + q * 4]) = pk;
    }
}

// ---------- final fused GEMM: out = relu([Zb|Vb] @ Bt^T - 0.05), K=320, bf16 MFMA ----------
// A-operands LDS-staged once per block (shared by all 4 waves), XOR-swizzled;
// B (Bt, 160KB total) stays global — identical across blocks, L2-resident.
__global__ __launch_bounds__(256) void k_out(const u16* __restrict__ Zb,
                                             const u16* __restrict__ Vb,
                                             const u16* __restrict__ Bt,
                                             float* __restrict__ out, int n) {
    __shared__ __align__(16) u16 sA[64 * 256];   // 32 KB, rows 512B, swizzled
    __shared__ __align__(16) u16 sV[64 * 64];    //  8 KB, rows 128B, swizzled
    const int t = threadIdx.x;
    const int w = t >> 6;
    const int lane = t & 63;
    const int m16 = lane & 15;          // A row / D col within tile
    const int quad = lane >> 4;         // k-subblock / D row group
    const int nb = blockIdx.x * 64;

    // stage Zb tile: 2048 chunks of 16B, 8 iters, coalesced, swizzled dest
#pragma unroll
    for (int i = 0; i < 8; ++i) {
        int c = i * 256 + t;
        int row = c >> 5, col = c & 31;
        int gr = nb + row; if (gr >= n) gr = n - 1;
        uint4 pk = *reinterpret_cast<const uint4*>(Zb + (size_t)gr * 256 + col * 8);
        *reinterpret_cast<uint4*>((char*)sA + row * 512 + ((col ^ (row & 7)) << 4)) = pk;
    }
    // stage Vb tile: 512 chunks of 16B, 2 iters
#pragma unroll
    for (int i = 0; i < 2; ++i) {
        int c = i * 256 + t;
        int row = c >> 3, col = c & 7;
        int gr = nb + row; if (gr >= n) gr = n - 1;
        uint4 pk = *reinterpret_cast<const uint4*>(Vb + (size_t)gr * 64 + col * 8);
        *reinterpret_cast<uint4*>((char*)sV + row * 128 + ((col ^ (row & 7)) << 4)) = pk;
    }
    __syncthreads();

    f32x4 acc[4][4];
#pragma unroll
    for (int mt = 0; mt < 4; ++mt)
#pragma unroll
        for (int nt = 0; nt < 4; ++nt)
            acc[mt][nt] = (f32x4){0.f, 0.f, 0.f, 0.f};

    const u16* bbase4[4];
#pragma unroll
    for (int nt = 0; nt < 4; ++nt)
        bbase4[nt] = Bt + (size_t)(w * 64 + nt * 16 + m16) * 320 + quad * 8;

    const u32 asw = (u32)(m16 & 7) << 4;

    for (int ks = 0; ks < 8; ++ks) {
        bf16x8 a[4], b[4];
#pragma unroll
        for (int mt = 0; mt < 4; ++mt)
            a[mt] = *reinterpret_cast<const bf16x8*>(
                (char*)sA + (u32)(mt * 16 + m16) * 512 +
                (((u32)(ks * 64 + quad * 16)) ^ asw));
#pragma unroll
        for (int nt = 0; nt < 4; ++nt)
            b[nt] = *reinterpret_cast<const bf16x8*>(bbase4[nt] + ks * 32);
#pragma unroll
        for (int mt = 0; mt < 4; ++mt)
#pragma unroll
            for (int nt = 0; nt < 4; ++nt)
                acc[mt][nt] = __builtin_amdgcn_mfma_f32_16x16x32_bf16(
                    a[mt], b[nt], acc[mt][nt], 0, 0, 0);
    }
#pragma unroll
    for (int ks = 8; ks < 10; ++ks) {
        bf16x8 a[4], b[4];
#pragma unroll
        for (int mt = 0; mt < 4; ++mt)
            a[mt] = *reinterpret_cast<const bf16x8*>(
                (char*)sV + (u32)(mt * 16 + m16) * 128 +
                (((u32)((ks - 8) * 64 + quad * 16)) ^ asw));
#pragma unroll
        for (int nt = 0; nt < 4; ++nt)
            b[nt] = *reinterpret_cast<const bf16x8*>(bbase4[nt] + ks * 32);
#pragma unroll
        for (int mt = 0; mt < 4; ++mt)
#pragma unroll
            for (int nt = 0; nt < 4; ++nt)
                acc[mt][nt] = __builtin_amdgcn_mfma_f32_16x16x32_bf16(
                    a[mt], b[nt], acc[mt][nt], 0, 0, 0);
    }

#pragma unroll
    for (int mt = 0; mt < 4; ++mt) {
#pragma unroll
        for (int r = 0; r < 4; ++r) {
            int row = nb + mt * 16 + quad * 4 + r;
            if (row < n) {
#pragma unroll
                for (int nt = 0; nt < 4; ++nt) {
                    int col = w * 64 + nt * 16 + m16;
                    out[(size_t)row * 256 + col] =
                        fmaxf(acc[mt][nt][r] - 0.05f, 0.f);
                }
            }
        }
    }
}

extern "C" void kernel_launch(void* const* d_in, const int* in_sizes, int n_in,
                              void* d_out, int out_size, void* d_ws, size_t ws_size,
                              hipStream_t stream) {
    const float* Z  = (const float*)d_in[0];
    const float* U  = (const float*)d_in[1];
    const float* Dm = (const float*)d_in[2];
    const float* hw = (const float*)d_in[3];
    const int*   ei = (const int*)d_in[4];
    const int n = in_sizes[0] / 256;       // 100000
    const int E = in_sizes[4] / 2;         // 1700000
    float* out = (float*)d_out;
    const int nbuck = (n + 255) >> 8;      // 391 (<= 512)

    // ws layout (~98 MB), lifetime-aliased:
    //   ZUb  fp32 n*64   (25.6 MB)  k_zumm -> k_agg
    //   Zb   bf16 n*256  (51.2 MB)  k_zumm -> k_out; OVERLAYS (dead after k_bucket):
    //        part int E (6.8 MB) | cnt2 int PB*nbuck | pre2 int PB*nbuck
    //   Vb   bf16 n*64   (12.8 MB)  k_agg -> k_out
    //   G, A fp32 64K ea; Bt bf16 256*320; U2t bf16 64*256
    //   esrc int E (6.8 MB)  k_bucket -> k_agg
    //   off, cnt int n; tot, bbase int nbuck
    char* wp = (char*)d_ws;
    float* ZUb  = (float*)wp;
    u16* Zb     = (u16*)(wp + (size_t)n * 256);
    int* part   = (int*)Zb;                 // aliases Zb (dead before k_zumm)
    int* cnt2   = part + E;
    int* pre2   = cnt2 + PB * nbuck;
    u16* Vb     = Zb + (size_t)n * 256;
    float* G    = (float*)(Vb + (size_t)n * 64);
    float* A    = G + 65536;
    u16* Bt     = (u16*)(A + 65536);
    u16* U2t    = Bt + 256 * 320;
    int* esrc   = (int*)(U2t + 64 * 256);
    int* off    = esrc + E;
    int* cnt    = off + n;
    int* tot    = cnt + n;
    int* bbase  = tot + nbuck;

    // prep (tiny)
    k_prep1<<<256, 256, 0, stream>>>(Dm, G);
    k_prep2<<<256, 256, 0, stream>>>(Dm, G, A);
    k_prep3<<<256, 256, 0, stream>>>(A, Bt);
    k_prep4<<<64, 256, 0, stream>>>(U, A, Bt);
    k_prep5<<<64, 256, 0, stream>>>(U, U2t);

    // CSR build (before k_zumm: part/cnt2/pre2 alias Zb)
    k_cnt1<<<PB, 256, 0, stream>>>(ei, cnt2, E, nbuck);
    k_cscan1<<<nbuck, 256, 0, stream>>>(cnt2, pre2, tot, nbuck);
    k_cscan2<<<1, 512, 0, stream>>>(tot, bbase, nbuck);
    k_place<<<PB, 256, 0, stream>>>(ei, pre2, bbase, part, E, nbuck);
    k_bucket<<<nbuck, 256, 0, stream>>>(part, tot, bbase, off, cnt, esrc, n);

    // main pipeline (k_cast fused into k_zumm's staging loop)
    k_zumm<<<(n + 63) / 64, 256, 0, stream>>>(Z, U2t, ZUb, Zb, n);
    k_agg<<<(n + 3) / 4, 256, 0, stream>>>(ZUb, esrc, off, cnt, hw, Vb, n);
    k_out<<<(n + 63) / 64, 256, 0, stream>>>(Zb, Vb, Bt, out, n);
}

// Round 2
// 443.589 us; speedup vs baseline: 1.0601x; 1.0026x over previous
//
#include <hip/hip_runtime.h>
#include <stdint.h>

// WhiteboxGATBlock: N=100000, D=256, K=4, R=16, E=1700000 (1.6M rand + 100k self-loops)
// All tensors fp32. Algebra:
//   M = 0.5*(D - (D^T D) D), A = I + M
//   H = 0.5*Z + 0.5*V@W  (V = head-weighted normalized attention agg, W[j][d]=U[j>>4][d][j&15])
//   out = relu(H@A - 0.05) = relu( Z@(0.5A) + V@(0.5*W@A) - 0.05 )
// => fused MFMA GEMM K=320 over [Zb | Vb] @ Bt. ZU for attention logits is ALSO an MFMA
//    GEMM (bf16 in, fp32 acc).
// Edge softmax: shift-invariant; self-loop guarantees denom > 0; fp32-safe without segmax.
// CSR build: deterministic two-level partition (bucket = dst>>8), LDS cursors only.
//
// R1: LDS-staged k_out/k_zumm (XOR-swizzled), k_cast fused into k_zumm. 470->445us.
// R2 change (k_agg = top dispatch, 78us, FETCH 190MB, VALU 51%, random 256B/edge gather):
//   ZU stored as bf16 (it is computed from bf16 inputs anyway). Edge gather payload
//   halves to 128B = 1 cache line; zd read + k_zumm ZU write also halve. bf16->f32
//   expansion is 1 shift/value in-register; dot + weighted accumulation stay fp32.

typedef unsigned short u16;
typedef unsigned int u32;
typedef __attribute__((ext_vector_type(8))) short bf16x8;   // 4 VGPRs, MFMA A/B frag
typedef __attribute__((ext_vector_type(4))) float f32x4;    // MFMA C/D frag

#define PB 256   // partition blocks

__device__ __forceinline__ u16 f2bf(float f) {
    u32 u = __float_as_uint(f);
    u32 r = u + 0x7fffu + ((u >> 16) & 1u);   // RNE
    return (u16)(r >> 16);
}
__device__ __forceinline__ float bl(u32 p) { return __uint_as_float(p << 16); }
__device__ __forceinline__ float bh(u32 p) { return __uint_as_float(p & 0xffff0000u); }

// ---------- prep: G = D^T D (256x256) ----------
__global__ void k_prep1(const float* __restrict__ D, float* __restrict__ G) {
    int i = blockIdx.x, j = threadIdx.x;
    float acc = 0.f;
    for (int d = 0; d < 256; ++d)
        acc += D[d * 256 + i] * D[d * 256 + j];
    G[i * 256 + j] = acc;
}

// ---------- prep: A = I + 0.5*(D - G@D)  (fp32) ----------
__global__ void k_prep2(const float* __restrict__ D, const float* __restrict__ G,
                        float* __restrict__ A) {
    int t = blockIdx.x, j = threadIdx.x;   // row t, col j
    float acc = 0.f;
    for (int u = 0; u < 256; ++u)
        acc += G[t * 256 + u] * D[u * 256 + j];
    A[t * 256 + j] = 0.5f * (D[t * 256 + j] - acc) + (t == j ? 1.f : 0.f);
}

// ---------- prep: Bt[c][k] = bf16(0.5*A[k][c]) for k<256 (B stored [col][k], 320-stride) ----------
__global__ void k_prep3(const float* __restrict__ A, u16* __restrict__ Bt) {
    int c = blockIdx.x, k = threadIdx.x;
    Bt[c * 320 + k] = f2bf(0.5f * A[k * 256 + c]);
}

// ---------- prep: Bt[c][256+j] = bf16(0.5 * sum_d W[j][d]*A[d][c]) ----------
__global__ void k_prep4(const float* __restrict__ U, const float* __restrict__ A,
                        u16* __restrict__ Bt) {
    int j = blockIdx.x, c = threadIdx.x;
    int k = j >> 4, r = j & 15;
    float acc = 0.f;
    for (int d = 0; d < 256; ++d)
        acc += U[k * 4096 + d * 16 + r] * A[d * 256 + c];
    Bt[c * 320 + 256 + j] = f2bf(0.5f * acc);
}

// ---------- prep: U2t[j][d] = bf16(U[j>>4][d][j&15])  (64x256, B-operand for k_zumm) ----------
__global__ void k_prep5(const float* __restrict__ U, u16* __restrict__ U2t) {
    int j = blockIdx.x, d = threadIdx.x;
    U2t[j * 256 + d] = f2bf(U[(j >> 4) * 4096 + d * 16 + (j & 15)]);
}

// ---------- partition pass 1: per-block histogram over coarse buckets ----------
__global__ __launch_bounds__(256) void k_cnt1(const int* __restrict__ ei,
                                              int* __restrict__ cnt2, int E, int nbuck) {
    __shared__ int h[512];
    int t = threadIdx.x, b = blockIdx.x;
    for (int i = t; i < nbuck; i += 256) h[i] = 0;
    __syncthreads();
    int per = (E + PB - 1) / PB;
    int lo = b * per;
    int hi = lo + per; if (hi > E) hi = E;
    for (int e = lo + t; e < hi; e += 256)
        atomicAdd(&h[ei[E + e] >> 8], 1);
    __syncthreads();
    for (int i = t; i < nbuck; i += 256)
        cnt2[b * nbuck + i] = h[i];
}

// ---------- partition pass 2a: per-bucket scan across blocks ----------
__global__ __launch_bounds__(256) void k_cscan1(const int* __restrict__ cnt2,
                                                int* __restrict__ pre2,
                                                int* __restrict__ tot, int nbuck) {
    __shared__ int s[256];
    int t = threadIdx.x, b = blockIdx.x;
    int v = cnt2[t * nbuck + b];
    s[t] = v;
    __syncthreads();
    for (int o = 1; o < 256; o <<= 1) {
        int x = (t >= o) ? s[t - o] : 0;
        __syncthreads();
        s[t] += x;
        __syncthreads();
    }
    pre2[t * nbuck + b] = s[t] - v;
    if (t == 255) tot[b] = s[255];
}

// ---------- partition pass 2b: scan bucket totals ----------
__global__ __launch_bounds__(512) void k_cscan2(const int* __restrict__ tot,
                                                int* __restrict__ bbase, int nbuck) {
    __shared__ int s[512];
    int t = threadIdx.x;
    int v = (t < nbuck) ? tot[t] : 0;
    s[t] = v;
    __syncthreads();
    for (int o = 1; o < 512; o <<= 1) {
        int x = (t >= o) ? s[t - o] : 0;
        __syncthreads();
        s[t] += x;
        __syncthreads();
    }
    if (t < nbuck) bbase[t] = s[t] - v;
}

// ---------- partition pass 3: place packed (src<<8 | dst&255) into coarse buckets ----------
__global__ __launch_bounds__(256) void k_place(const int* __restrict__ ei,
                                               const int* __restrict__ pre2,
                                               const int* __restrict__ bbase,
                                               int* __restrict__ part, int E, int nbuck) {
    __shared__ int baseS[512];
    __shared__ int cur[512];
    int t = threadIdx.x, b = blockIdx.x;
    for (int i = t; i < nbuck; i += 256) {
        baseS[i] = bbase[i] + pre2[b * nbuck + i];
        cur[i] = 0;
    }
    __syncthreads();
    int per = (E + PB - 1) / PB;
    int lo = b * per;
    int hi = lo + per; if (hi > E) hi = E;
    for (int e = lo + t; e < hi; e += 256) {
        int s = ei[e];
        int d = ei[E + e];
        int bk = d >> 8;
        int r = atomicAdd(&cur[bk], 1);          // LDS atomic
        part[baseS[bk] + r] = (s << 8) | (d & 255);
    }
}

// ---------- partition pass 4: within-bucket CSR finalize (off/cnt/esrc), LDS cursors ----------
__global__ __launch_bounds__(256) void k_bucket(const int* __restrict__ part,
                                                const int* __restrict__ tot,
                                                const int* __restrict__ bbase,
                                                int* __restrict__ off,
                                                int* __restrict__ cnt,
                                                int* __restrict__ esrc, int n) {
    __shared__ int ncnt[256], excl[256], cur[256], sc[256];
    int t = threadIdx.x, b = blockIdx.x;
    ncnt[t] = 0;
    cur[t] = 0;
    __syncthreads();
    int base = bbase[b], m = tot[b];
    for (int i = t; i < m; i += 256)
        atomicAdd(&ncnt[part[base + i] & 255], 1);
    __syncthreads();
    int v = ncnt[t];
    sc[t] = v;
    __syncthreads();
    for (int o = 1; o < 256; o <<= 1) {
        int x = (t >= o) ? sc[t - o] : 0;
        __syncthreads();
        sc[t] += x;
        __syncthreads();
    }
    excl[t] = sc[t] - v;
    int node = b * 256 + t;
    if (node < n) {
        off[node] = base + excl[t];
        cnt[node] = v;
    }
    __syncthreads();
    for (int i = t; i < m; i += 256) {
        int pk = part[base + i];
        int j = pk & 255;
        int r = atomicAdd(&cur[j], 1);           // LDS atomic
        esrc[base + excl[j] + r] = pk >> 8;
    }
}

// ---------- ZU = bf16(Z) @ U2t^T via MFMA (bf16 out), fused cast (emits Zb) ----------
// block = 4 waves over a shared 64-row tile; wave w computes rows w*16..w*16+15.
// Staging: read Z fp32, RNE->bf16, ds_write XOR-swizzled LDS tile + linear Zb global.
__global__ __launch_bounds__(256) void k_zumm(const float* __restrict__ Z,
                                              const u16* __restrict__ U2t,
                                              u16* __restrict__ ZUb,
                                              u16* __restrict__ Zb, int n) {
    __shared__ __align__(16) u16 sA[64 * 256];   // 32 KB, rows 512B, swizzled
    const int t = threadIdx.x;
    const int w = t >> 6;
    const int lane = t & 63;
    const int m16 = lane & 15;
    const int quad = lane >> 4;
    const int nb = blockIdx.x * 64;

    // stage + cast: 64 rows x 32 chunks(16B bf16 = 8 fp32) = 2048 chunks, 8 iters
#pragma unroll
    for (int i = 0; i < 8; ++i) {
        int c = i * 256 + t;
        int row = c >> 5, col = c & 31;
        int grow = nb + row;
        int gr = grow < n ? grow : n - 1;
        const float4* zp = reinterpret_cast<const float4*>(Z + (size_t)gr * 256 + col * 8);
        float4 a = zp[0], b = zp[1];
        uint4 pk;
        pk.x = (u32)f2bf(a.x) | ((u32)f2bf(a.y) << 16);
        pk.y = (u32)f2bf(a.z) | ((u32)f2bf(a.w) << 16);
        pk.z = (u32)f2bf(b.x) | ((u32)f2bf(b.y) << 16);
        pk.w = (u32)f2bf(b.z) | ((u32)f2bf(b.w) << 16);
        // swizzle: chunk col ^= row&7  (spreads the 512B-stride column across banks)
        *reinterpret_cast<uint4*>((char*)sA + row * 512 + ((col ^ (row & 7)) << 4)) = pk;
        if (grow < n)
            *reinterpret_cast<uint4*>(Zb + (size_t)grow * 256 + col * 8) = pk;
    }
    __syncthreads();

    f32x4 acc[4];
#pragma unroll
    for (int nt = 0; nt < 4; ++nt) acc[nt] = (f32x4){0.f, 0.f, 0.f, 0.f};

    const int arow = w * 16 + m16;
    const u32 abase = (u32)arow * 512;
    const u32 asw = (u32)(m16 & 7) << 4;

    for (int ks = 0; ks < 8; ++ks) {
        bf16x8 a = *reinterpret_cast<const bf16x8*>(
            (char*)sA + abase + (((u32)(ks * 64 + quad * 16)) ^ asw));
#pragma unroll
        for (int nt = 0; nt < 4; ++nt) {
            bf16x8 b = *reinterpret_cast<const bf16x8*>(
                U2t + (size_t)(nt * 16 + m16) * 256 + ks * 32 + quad * 8);
            acc[nt] = __builtin_amdgcn_mfma_f32_16x16x32_bf16(a, b, acc[nt], 0, 0, 0);
        }
    }
    // D: row=quad*4+r (node), col=m16 (output within nt tile); store bf16
#pragma unroll
    for (int r = 0; r < 4; ++r) {
        int node = nb + w * 16 + quad * 4 + r;
        if (node < n) {
#pragma unroll
            for (int nt = 0; nt < 4; ++nt)
                ZUb[(size_t)node * 64 + nt * 16 + m16] = f2bf(acc[nt][r]);
        }
    }
}

// ---------- per-node aggregation: 1 wave/node, 4 edges in flight; emits bf16 V ----------
// lane = g*16+q: group g handles edge c0+g, lane q holds dims 4q..4q+3 (uint2 bf16x4)
__global__ __launch_bounds__(256) void k_agg(const u16* __restrict__ ZUb,
                                             const int* __restrict__ esrc,
                                             const int* __restrict__ off,
                                             const int* __restrict__ cnt,
                                             const float* __restrict__ hwp,
                                             u16* __restrict__ Vb, int n) {
    int node = blockIdx.x * 4 + (threadIdx.x >> 6);
    int lane = threadIdx.x & 63;
    if (node >= n) return;
    const int q = lane & 15;
    const int g = lane >> 4;
    uint2 zdp = *reinterpret_cast<const uint2*>(ZUb + (size_t)node * 64 + q * 4);
    float zd0 = bl(zdp.x), zd1 = bh(zdp.x), zd2 = bl(zdp.y), zd3 = bh(zdp.y);
    int base = off[node];
    int deg = cnt[node];

    float ax = 0.f, ay = 0.f, az = 0.f, aw = 0.f, ssum = 0.f;
    for (int c0 = 0; c0 < deg; c0 += 4) {
        int e = c0 + g;
        bool valid = e < deg;
        int s = valid ? esrc[base + e] : 0;
        uint2 zsp = *reinterpret_cast<const uint2*>(ZUb + (size_t)s * 64 + q * 4);
        float z0 = bl(zsp.x), z1 = bh(zsp.x), z2 = bl(zsp.y), z3 = bh(zsp.y);
        float p = z0 * zd0 + z1 * zd1 + z2 * zd2 + z3 * zd3;
        p += __shfl_xor(p, 1);
        p += __shfl_xor(p, 2);              // head dot across 4-lane subgroup
        float ew = valid ? __expf(p * 0.25f) : 0.f;   // / sqrt(R)=4
        ax += ew * z0; ay += ew * z1;
        az += ew * z2; aw += ew * z3;
        ssum += ew;
    }
    ax += __shfl_xor(ax, 16); ax += __shfl_xor(ax, 32);
    ay += __shfl_xor(ay, 16); ay += __shfl_xor(ay, 32);
    az += __shfl_xor(az, 16); az += __shfl_xor(az, 32);
    aw += __shfl_xor(aw, 16); aw += __shfl_xor(aw, 32);
    ssum += __shfl_xor(ssum, 16); ssum += __shfl_xor(ssum, 32);

    if (g == 0) {
        float h0 = hwp[0], h1 = hwp[1], h2 = hwp[2], h3 = hwp[3];
        float mx = fmaxf(fmaxf(h0, h1), fmaxf(h2, h3));
        float e0 = __expf(h0 - mx), e1 = __expf(h1 - mx),
              e2 = __expf(h2 - mx), e3 = __expf(h3 - mx);
        float es = e0 + e1 + e2 + e3;
        int hd = q >> 2;
        float wk = (hd == 0 ? e0 : hd == 1 ? e1 : hd == 2 ? e2 : e3) / es;
        float inv = wk / ssum;
        uint2 pk;
        pk.x = (u32)f2bf(ax * inv) | ((u32)f2bf(ay * inv) << 16);
        pk.y = (u32)f2bf(az * inv) | ((u32)f2bf(aw * inv) << 16);
        *reinterpret_cast<uint2*>(&Vb[(size_t)node * 64 + q * 4]) = pk;
    }
}

// ---------- final fused GEMM: out = relu([Zb|Vb] @ Bt^T - 0.05), K=320, bf16 MFMA ----------
// A-operands LDS-staged once per block (shared by all 4 waves), XOR-swizzled;
// B (Bt, 160KB total) stays global — identical across blocks, L2-resident.
__global__ __launch_bounds__(256) void k_out(const u16* __restrict__ Zb,
                                             const u16* __restrict__ Vb,
                                             const u16* __restrict__ Bt,
                                             float* __restrict__ out, int n) {
    __shared__ __align__(16) u16 sA[64 * 256];   // 32 KB, rows 512B, swizzled
    __shared__ __align__(16) u16 sV[64 * 64];    //  8 KB, rows 128B, swizzled
    const int t = threadIdx.x;
    const int w = t >> 6;
    const int lane = t & 63;
    const int m16 = lane & 15;          // A row / D col within tile
    const int quad = lane >> 4;         // k-subblock / D row group
    const int nb = blockIdx.x * 64;

    // stage Zb tile: 2048 chunks of 16B, 8 iters, coalesced, swizzled dest
#pragma unroll
    for (int i = 0; i < 8; ++i) {
        int c = i * 256 + t;
        int row = c >> 5, col = c & 31;
        int gr = nb + row; if (gr >= n) gr = n - 1;
        uint4 pk = *reinterpret_cast<const uint4*>(Zb + (size_t)gr * 256 + col * 8);
        *reinterpret_cast<uint4*>((char*)sA + row * 512 + ((col ^ (row & 7)) << 4)) = pk;
    }
    // stage Vb tile: 512 chunks of 16B, 2 iters
#pragma unroll
    for (int i = 0; i < 2; ++i) {
        int c = i * 256 + t;
        int row = c >> 3, col = c & 7;
        int gr = nb + row; if (gr >= n) gr = n - 1;
        uint4 pk = *reinterpret_cast<const uint4*>(Vb + (size_t)gr * 64 + col * 8);
        *reinterpret_cast<uint4*>((char*)sV + row * 128 + ((col ^ (row & 7)) << 4)) = pk;
    }
    __syncthreads();

    f32x4 acc[4][4];
#pragma unroll
    for (int mt = 0; mt < 4; ++mt)
#pragma unroll
        for (int nt = 0; nt < 4; ++nt)
            acc[mt][nt] = (f32x4){0.f, 0.f, 0.f, 0.f};

    const u16* bbase4[4];
#pragma unroll
    for (int nt = 0; nt < 4; ++nt)
        bbase4[nt] = Bt + (size_t)(w * 64 + nt * 16 + m16) * 320 + quad * 8;

    const u32 asw = (u32)(m16 & 7) << 4;

    for (int ks = 0; ks < 8; ++ks) {
        bf16x8 a[4], b[4];
#pragma unroll
        for (int mt = 0; mt < 4; ++mt)
            a[mt] = *reinterpret_cast<const bf16x8*>(
                (char*)sA + (u32)(mt * 16 + m16) * 512 +
                (((u32)(ks * 64 + quad * 16)) ^ asw));
#pragma unroll
        for (int nt = 0; nt < 4; ++nt)
            b[nt] = *reinterpret_cast<const bf16x8*>(bbase4[nt] + ks * 32);
#pragma unroll
        for (int mt = 0; mt < 4; ++mt)
#pragma unroll
            for (int nt = 0; nt < 4; ++nt)
                acc[mt][nt] = __builtin_amdgcn_mfma_f32_16x16x32_bf16(
                    a[mt], b[nt], acc[mt][nt], 0, 0, 0);
    }
#pragma unroll
    for (int ks = 8; ks < 10; ++ks) {
        bf16x8 a[4], b[4];
#pragma unroll
        for (int mt = 0; mt < 4; ++mt)
            a[mt] = *reinterpret_cast<const bf16x8*>(
                (char*)sV + (u32)(mt * 16 + m16) * 128 +
                (((u32)((ks - 8) * 64 + quad * 16)) ^ asw));
#pragma unroll
        for (int nt = 0; nt < 4; ++nt)
            b[nt] = *reinterpret_cast<const bf16x8*>(bbase4[nt] + ks * 32);
#pragma unroll
        for (int mt = 0; mt < 4; ++mt)
#pragma unroll
            for (int nt = 0; nt < 4; ++nt)
                acc[mt][nt] = __builtin_amdgcn_mfma_f32_16x16x32_bf16(
                    a[mt], b[nt], acc[mt][nt], 0, 0, 0);
    }

#pragma unroll
    for (int mt = 0; mt < 4; ++mt) {
#pragma unroll
        for (int r = 0; r < 4; ++r) {
            int row = nb + mt * 16 + quad * 4 + r;
            if (row < n) {
#pragma unroll
                for (int nt = 0; nt < 4; ++nt) {
                    int col = w * 64 + nt * 16 + m16;
                    out[(size_t)row * 256 + col] =
                        fmaxf(acc[mt][nt][r] - 0.05f, 0.f);
                }
            }
        }
    }
}

extern "C" void kernel_launch(void* const* d_in, const int* in_sizes, int n_in,
                              void* d_out, int out_size, void* d_ws, size_t ws_size,
                              hipStream_t stream) {
    const float* Z  = (const float*)d_in[0];
    const float* U  = (const float*)d_in[1];
    const float* Dm = (const float*)d_in[2];
    const float* hw = (const float*)d_in[3];
    const int*   ei = (const int*)d_in[4];
    const int n = in_sizes[0] / 256;       // 100000
    const int E = in_sizes[4] / 2;         // 1700000
    float* out = (float*)d_out;
    const int nbuck = (n + 255) >> 8;      // 391 (<= 512)

    // ws layout (~85 MB), lifetime-aliased:
    //   ZUb  bf16 n*64   (12.8 MB)  k_zumm -> k_agg
    //   Zb   bf16 n*256  (51.2 MB)  k_zumm -> k_out; OVERLAYS (dead after k_bucket):
    //        part int E (6.8 MB) | cnt2 int PB*nbuck | pre2 int PB*nbuck
    //   Vb   bf16 n*64   (12.8 MB)  k_agg -> k_out
    //   G, A fp32 64K ea; Bt bf16 256*320; U2t bf16 64*256
    //   esrc int E (6.8 MB)  k_bucket -> k_agg
    //   off, cnt int n; tot, bbase int nbuck
    char* wp = (char*)d_ws;
    u16* ZUb    = (u16*)wp;
    u16* Zb     = (u16*)(wp + (size_t)n * 128);
    int* part   = (int*)Zb;                 // aliases Zb (dead before k_zumm)
    int* cnt2   = part + E;
    int* pre2   = cnt2 + PB * nbuck;
    u16* Vb     = Zb + (size_t)n * 256;
    float* G    = (float*)(Vb + (size_t)n * 64);
    float* A    = G + 65536;
    u16* Bt     = (u16*)(A + 65536);
    u16* U2t    = Bt + 256 * 320;
    int* esrc   = (int*)(U2t + 64 * 256);
    int* off    = esrc + E;
    int* cnt    = off + n;
    int* tot    = cnt + n;
    int* bbase  = tot + nbuck;

    // prep (tiny)
    k_prep1<<<256, 256, 0, stream>>>(Dm, G);
    k_prep2<<<256, 256, 0, stream>>>(Dm, G, A);
    k_prep3<<<256, 256, 0, stream>>>(A, Bt);
    k_prep4<<<64, 256, 0, stream>>>(U, A, Bt);
    k_prep5<<<64, 256, 0, stream>>>(U, U2t);

    // CSR build (before k_zumm: part/cnt2/pre2 alias Zb)
    k_cnt1<<<PB, 256, 0, stream>>>(ei, cnt2, E, nbuck);
    k_cscan1<<<nbuck, 256, 0, stream>>>(cnt2, pre2, tot, nbuck);
    k_cscan2<<<1, 512, 0, stream>>>(tot, bbase, nbuck);
    k_place<<<PB, 256, 0, stream>>>(ei, pre2, bbase, part, E, nbuck);
    k_bucket<<<nbuck, 256, 0, stream>>>(part, tot, bbase, off, cnt, esrc, n);

    // main pipeline (k_cast fused into k_zumm's staging loop)
    k_zumm<<<(n + 63) / 64, 256, 0, stream>>>(Z, U2t, ZUb, Zb, n);
    k_agg<<<(n + 3) / 4, 256, 0, stream>>>(ZUb, esrc, off, cnt, hw, Vb, n);
    k_out<<<(n + 63) / 64, 256, 0, stream>>>(Zb, Vb, Bt, out, n);
}

// Round 3
// 416.739 us; speedup vs baseline: 1.1284x; 1.0644x over previous
//
#include <hip/hip_runtime.h>
#include <stdint.h>

// WhiteboxGATBlock: N=100000, D=256, K=4, R=16, E=1700000 (1.6M rand + 100k self-loops)
// All tensors fp32. Algebra:
//   M = 0.5*(D - (D^T D) D), A = I + M
//   H = 0.5*Z + 0.5*V@W  (V = head-weighted normalized attention agg, W[j][d]=U[j>>4][d][j&15])
//   out = relu(H@A - 0.05) = relu( Z@(0.5A) + V@(0.5*W@A) - 0.05 )
// => fused MFMA GEMM K=320 over [Zb | Vb] @ Bt. ZU for attention logits is ALSO an MFMA
//    GEMM (bf16 in, fp32 acc).
// Edge softmax: shift-invariant; self-loop guarantees denom > 0; fp32-safe without segmax.
// CSR build: deterministic two-level partition (bucket = dst>>8), LDS cursors only.
//
// R1: LDS-staged k_out/k_zumm (XOR-swizzled), k_cast fused into k_zumm. 470->445us.
// R2: ZU stored bf16 (edge gather payload 256B->128B). k_agg off top; absmax improved.
// R3 change (k_zumm top @77us, VGPR=44 => staging serialized on HBM latency,
//            hbm 19% / VALU 5% / Mfma 1.5% / occ 31% = latency-bound):
//   - k_zumm/k_out: register-staged loads — issue ALL tile loads into reg arrays
//     first, then pack/ds_write (T14 issue-early write-late). launch_bounds(256,4).
//   - k_agg: 2-deep esrc / 1-deep ZUb-gather software pipeline (VGPR 16 showed
//     zero compiler pipelining of the dependent index->gather chain).

typedef unsigned short u16;
typedef unsigned int u32;
typedef __attribute__((ext_vector_type(8))) short bf16x8;   // 4 VGPRs, MFMA A/B frag
typedef __attribute__((ext_vector_type(4))) float f32x4;    // MFMA C/D frag

#define PB 256   // partition blocks

__device__ __forceinline__ u16 f2bf(float f) {
    u32 u = __float_as_uint(f);
    u32 r = u + 0x7fffu + ((u >> 16) & 1u);   // RNE
    return (u16)(r >> 16);
}
__device__ __forceinline__ float bl(u32 p) { return __uint_as_float(p << 16); }
__device__ __forceinline__ float bh(u32 p) { return __uint_as_float(p & 0xffff0000u); }

// ---------- prep: G = D^T D (256x256) ----------
__global__ void k_prep1(const float* __restrict__ D, float* __restrict__ G) {
    int i = blockIdx.x, j = threadIdx.x;
    float acc = 0.f;
    for (int d = 0; d < 256; ++d)
        acc += D[d * 256 + i] * D[d * 256 + j];
    G[i * 256 + j] = acc;
}

// ---------- prep: A = I + 0.5*(D - G@D)  (fp32) ----------
__global__ void k_prep2(const float* __restrict__ D, const float* __restrict__ G,
                        float* __restrict__ A) {
    int t = blockIdx.x, j = threadIdx.x;   // row t, col j
    float acc = 0.f;
    for (int u = 0; u < 256; ++u)
        acc += G[t * 256 + u] * D[u * 256 + j];
    A[t * 256 + j] = 0.5f * (D[t * 256 + j] - acc) + (t == j ? 1.f : 0.f);
}

// ---------- prep: Bt[c][k] = bf16(0.5*A[k][c]) for k<256 (B stored [col][k], 320-stride) ----------
__global__ void k_prep3(const float* __restrict__ A, u16* __restrict__ Bt) {
    int c = blockIdx.x, k = threadIdx.x;
    Bt[c * 320 + k] = f2bf(0.5f * A[k * 256 + c]);
}

// ---------- prep: Bt[c][256+j] = bf16(0.5 * sum_d W[j][d]*A[d][c]) ----------
__global__ void k_prep4(const float* __restrict__ U, const float* __restrict__ A,
                        u16* __restrict__ Bt) {
    int j = blockIdx.x, c = threadIdx.x;
    int k = j >> 4, r = j & 15;
    float acc = 0.f;
    for (int d = 0; d < 256; ++d)
        acc += U[k * 4096 + d * 16 + r] * A[d * 256 + c];
    Bt[c * 320 + 256 + j] = f2bf(0.5f * acc);
}

// ---------- prep: U2t[j][d] = bf16(U[j>>4][d][j&15])  (64x256, B-operand for k_zumm) ----------
__global__ void k_prep5(const float* __restrict__ U, u16* __restrict__ U2t) {
    int j = blockIdx.x, d = threadIdx.x;
    U2t[j * 256 + d] = f2bf(U[(j >> 4) * 4096 + d * 16 + (j & 15)]);
}

// ---------- partition pass 1: per-block histogram over coarse buckets ----------
__global__ __launch_bounds__(256) void k_cnt1(const int* __restrict__ ei,
                                              int* __restrict__ cnt2, int E, int nbuck) {
    __shared__ int h[512];
    int t = threadIdx.x, b = blockIdx.x;
    for (int i = t; i < nbuck; i += 256) h[i] = 0;
    __syncthreads();
    int per = (E + PB - 1) / PB;
    int lo = b * per;
    int hi = lo + per; if (hi > E) hi = E;
    for (int e = lo + t; e < hi; e += 256)
        atomicAdd(&h[ei[E + e] >> 8], 1);
    __syncthreads();
    for (int i = t; i < nbuck; i += 256)
        cnt2[b * nbuck + i] = h[i];
}

// ---------- partition pass 2a: per-bucket scan across blocks ----------
__global__ __launch_bounds__(256) void k_cscan1(const int* __restrict__ cnt2,
                                                int* __restrict__ pre2,
                                                int* __restrict__ tot, int nbuck) {
    __shared__ int s[256];
    int t = threadIdx.x, b = blockIdx.x;
    int v = cnt2[t * nbuck + b];
    s[t] = v;
    __syncthreads();
    for (int o = 1; o < 256; o <<= 1) {
        int x = (t >= o) ? s[t - o] : 0;
        __syncthreads();
        s[t] += x;
        __syncthreads();
    }
    pre2[t * nbuck + b] = s[t] - v;
    if (t == 255) tot[b] = s[255];
}

// ---------- partition pass 2b: scan bucket totals ----------
__global__ __launch_bounds__(512) void k_cscan2(const int* __restrict__ tot,
                                                int* __restrict__ bbase, int nbuck) {
    __shared__ int s[512];
    int t = threadIdx.x;
    int v = (t < nbuck) ? tot[t] : 0;
    s[t] = v;
    __syncthreads();
    for (int o = 1; o < 512; o <<= 1) {
        int x = (t >= o) ? s[t - o] : 0;
        __syncthreads();
        s[t] += x;
        __syncthreads();
    }
    if (t < nbuck) bbase[t] = s[t] - v;
}

// ---------- partition pass 3: place packed (src<<8 | dst&255) into coarse buckets ----------
__global__ __launch_bounds__(256) void k_place(const int* __restrict__ ei,
                                               const int* __restrict__ pre2,
                                               const int* __restrict__ bbase,
                                               int* __restrict__ part, int E, int nbuck) {
    __shared__ int baseS[512];
    __shared__ int cur[512];
    int t = threadIdx.x, b = blockIdx.x;
    for (int i = t; i < nbuck; i += 256) {
        baseS[i] = bbase[i] + pre2[b * nbuck + i];
        cur[i] = 0;
    }
    __syncthreads();
    int per = (E + PB - 1) / PB;
    int lo = b * per;
    int hi = lo + per; if (hi > E) hi = E;
    for (int e = lo + t; e < hi; e += 256) {
        int s = ei[e];
        int d = ei[E + e];
        int bk = d >> 8;
        int r = atomicAdd(&cur[bk], 1);          // LDS atomic
        part[baseS[bk] + r] = (s << 8) | (d & 255);
    }
}

// ---------- partition pass 4: within-bucket CSR finalize (off/cnt/esrc), LDS cursors ----------
__global__ __launch_bounds__(256) void k_bucket(const int* __restrict__ part,
                                                const int* __restrict__ tot,
                                                const int* __restrict__ bbase,
                                                int* __restrict__ off,
                                                int* __restrict__ cnt,
                                                int* __restrict__ esrc, int n) {
    __shared__ int ncnt[256], excl[256], cur[256], sc[256];
    int t = threadIdx.x, b = blockIdx.x;
    ncnt[t] = 0;
    cur[t] = 0;
    __syncthreads();
    int base = bbase[b], m = tot[b];
    for (int i = t; i < m; i += 256)
        atomicAdd(&ncnt[part[base + i] & 255], 1);
    __syncthreads();
    int v = ncnt[t];
    sc[t] = v;
    __syncthreads();
    for (int o = 1; o < 256; o <<= 1) {
        int x = (t >= o) ? sc[t - o] : 0;
        __syncthreads();
        sc[t] += x;
        __syncthreads();
    }
    excl[t] = sc[t] - v;
    int node = b * 256 + t;
    if (node < n) {
        off[node] = base + excl[t];
        cnt[node] = v;
    }
    __syncthreads();
    for (int i = t; i < m; i += 256) {
        int pk = part[base + i];
        int j = pk & 255;
        int r = atomicAdd(&cur[j], 1);           // LDS atomic
        esrc[base + excl[j] + r] = pk >> 8;
    }
}

// ---------- ZU = bf16(Z) @ U2t^T via MFMA (bf16 out), fused cast (emits Zb) ----------
// block = 4 waves over a shared 64-row tile; wave w computes rows w*16..w*16+15.
// R3: register-staged — all 16 float4 loads issued before any pack/ds_write.
__global__ __launch_bounds__(256, 4) void k_zumm(const float* __restrict__ Z,
                                                 const u16* __restrict__ U2t,
                                                 u16* __restrict__ ZUb,
                                                 u16* __restrict__ Zb, int n) {
    __shared__ __align__(16) u16 sA[64 * 256];   // 32 KB, rows 512B, swizzled
    const int t = threadIdx.x;
    const int w = t >> 6;
    const int lane = t & 63;
    const int m16 = lane & 15;
    const int quad = lane >> 4;
    const int nb = blockIdx.x * 64;

    // phase 1: issue all 16 global loads (64 VGPRs of data in flight)
    float4 va[8], vb[8];
#pragma unroll
    for (int i = 0; i < 8; ++i) {
        int c = i * 256 + t;
        int row = c >> 5, col = c & 31;
        int grow = nb + row;
        int gr = grow < n ? grow : n - 1;
        const float4* zp = reinterpret_cast<const float4*>(Z + (size_t)gr * 256 + col * 8);
        va[i] = zp[0];
        vb[i] = zp[1];
    }
    // phase 2: pack + ds_write (swizzled) + linear Zb store
#pragma unroll
    for (int i = 0; i < 8; ++i) {
        int c = i * 256 + t;
        int row = c >> 5, col = c & 31;
        int grow = nb + row;
        uint4 pk;
        pk.x = (u32)f2bf(va[i].x) | ((u32)f2bf(va[i].y) << 16);
        pk.y = (u32)f2bf(va[i].z) | ((u32)f2bf(va[i].w) << 16);
        pk.z = (u32)f2bf(vb[i].x) | ((u32)f2bf(vb[i].y) << 16);
        pk.w = (u32)f2bf(vb[i].z) | ((u32)f2bf(vb[i].w) << 16);
        *reinterpret_cast<uint4*>((char*)sA + row * 512 + ((col ^ (row & 7)) << 4)) = pk;
        if (grow < n)
            *reinterpret_cast<uint4*>(Zb + (size_t)grow * 256 + col * 8) = pk;
    }
    __syncthreads();

    f32x4 acc[4];
#pragma unroll
    for (int nt = 0; nt < 4; ++nt) acc[nt] = (f32x4){0.f, 0.f, 0.f, 0.f};

    const int arow = w * 16 + m16;
    const u32 abase = (u32)arow * 512;
    const u32 asw = (u32)(m16 & 7) << 4;

    for (int ks = 0; ks < 8; ++ks) {
        bf16x8 a = *reinterpret_cast<const bf16x8*>(
            (char*)sA + abase + (((u32)(ks * 64 + quad * 16)) ^ asw));
#pragma unroll
        for (int nt = 0; nt < 4; ++nt) {
            bf16x8 b = *reinterpret_cast<const bf16x8*>(
                U2t + (size_t)(nt * 16 + m16) * 256 + ks * 32 + quad * 8);
            acc[nt] = __builtin_amdgcn_mfma_f32_16x16x32_bf16(a, b, acc[nt], 0, 0, 0);
        }
    }
    // D: row=quad*4+r (node), col=m16 (output within nt tile); store bf16
#pragma unroll
    for (int r = 0; r < 4; ++r) {
        int node = nb + w * 16 + quad * 4 + r;
        if (node < n) {
#pragma unroll
            for (int nt = 0; nt < 4; ++nt)
                ZUb[(size_t)node * 64 + nt * 16 + m16] = f2bf(acc[nt][r]);
        }
    }
}

// ---------- per-node aggregation: 1 wave/node, 4 edges in flight; emits bf16 V ----------
// lane = g*16+q: group g handles edge c0+g, lane q holds dims 4q..4q+3 (uint2 bf16x4)
// R3: 2-deep esrc index pipeline + 1-deep ZUb gather pipeline.
__global__ __launch_bounds__(256) void k_agg(const u16* __restrict__ ZUb,
                                             const int* __restrict__ esrc,
                                             const int* __restrict__ off,
                                             const int* __restrict__ cnt,
                                             const float* __restrict__ hwp,
                                             u16* __restrict__ Vb, int n) {
    int node = blockIdx.x * 4 + (threadIdx.x >> 6);
    int lane = threadIdx.x & 63;
    if (node >= n) return;
    const int q = lane & 15;
    const int g = lane >> 4;
    uint2 zdp = *reinterpret_cast<const uint2*>(ZUb + (size_t)node * 64 + q * 4);
    float zd0 = bl(zdp.x), zd1 = bh(zdp.x), zd2 = bl(zdp.y), zd3 = bh(zdp.y);
    int base = off[node];
    int deg = cnt[node];

    // prologue: s_k = esrc index for iteration k (edge 4k+g); z for iter 0 in flight
    int s0 = (g < deg) ? esrc[base + g] : 0;
    int s1 = (4 + g < deg) ? esrc[base + 4 + g] : 0;
    uint2 z0 = *reinterpret_cast<const uint2*>(ZUb + (size_t)s0 * 64 + q * 4);

    float ax = 0.f, ay = 0.f, az = 0.f, aw = 0.f, ssum = 0.f;
    for (int c0 = 0; c0 < deg; c0 += 4) {
        int e2 = c0 + 8 + g;
        int s2 = (e2 < deg) ? esrc[base + e2] : 0;          // index prefetch (k+2)
        uint2 z1 = *reinterpret_cast<const uint2*>(           // gather prefetch (k+1)
            ZUb + (size_t)s1 * 64 + q * 4);
        bool valid = (c0 + g) < deg;
        float v0 = bl(z0.x), v1 = bh(z0.x), v2 = bl(z0.y), v3 = bh(z0.y);
        float p = v0 * zd0 + v1 * zd1 + v2 * zd2 + v3 * zd3;
        p += __shfl_xor(p, 1);
        p += __shfl_xor(p, 2);              // head dot across 4-lane subgroup
        float ew = valid ? __expf(p * 0.25f) : 0.f;   // / sqrt(R)=4
        ax += ew * v0; ay += ew * v1;
        az += ew * v2; aw += ew * v3;
        ssum += ew;
        s1 = s2; z0 = z1;
    }
    ax += __shfl_xor(ax, 16); ax += __shfl_xor(ax, 32);
    ay += __shfl_xor(ay, 16); ay += __shfl_xor(ay, 32);
    az += __shfl_xor(az, 16); az += __shfl_xor(az, 32);
    aw += __shfl_xor(aw, 16); aw += __shfl_xor(aw, 32);
    ssum += __shfl_xor(ssum, 16); ssum += __shfl_xor(ssum, 32);

    if (g == 0) {
        float h0 = hwp[0], h1 = hwp[1], h2 = hwp[2], h3 = hwp[3];
        float mx = fmaxf(fmaxf(h0, h1), fmaxf(h2, h3));
        float e0 = __expf(h0 - mx), e1 = __expf(h1 - mx),
              e2 = __expf(h2 - mx), e3 = __expf(h3 - mx);
        float es = e0 + e1 + e2 + e3;
        int hd = q >> 2;
        float wk = (hd == 0 ? e0 : hd == 1 ? e1 : hd == 2 ? e2 : e3) / es;
        float inv = wk / ssum;
        uint2 pk;
        pk.x = (u32)f2bf(ax * inv) | ((u32)f2bf(ay * inv) << 16);
        pk.y = (u32)f2bf(az * inv) | ((u32)f2bf(aw * inv) << 16);
        *reinterpret_cast<uint2*>(&Vb[(size_t)node * 64 + q * 4]) = pk;
    }
}

// ---------- final fused GEMM: out = relu([Zb|Vb] @ Bt^T - 0.05), K=320, bf16 MFMA ----------
// A-operands LDS-staged once per block (shared by all 4 waves), XOR-swizzled;
// B (Bt, 160KB total) stays global — identical across blocks, L2-resident.
// R3: register-staged — all 10 uint4 loads issued before any ds_write.
__global__ __launch_bounds__(256, 4) void k_out(const u16* __restrict__ Zb,
                                                const u16* __restrict__ Vb,
                                                const u16* __restrict__ Bt,
                                                float* __restrict__ out, int n) {
    __shared__ __align__(16) u16 sA[64 * 256];   // 32 KB, rows 512B, swizzled
    __shared__ __align__(16) u16 sV[64 * 64];    //  8 KB, rows 128B, swizzled
    const int t = threadIdx.x;
    const int w = t >> 6;
    const int lane = t & 63;
    const int m16 = lane & 15;          // A row / D col within tile
    const int quad = lane >> 4;         // k-subblock / D row group
    const int nb = blockIdx.x * 64;

    // phase 1: issue all loads (8x Zb tile, 2x Vb tile)
    uint4 za[8], zv[2];
#pragma unroll
    for (int i = 0; i < 8; ++i) {
        int c = i * 256 + t;
        int row = c >> 5, col = c & 31;
        int gr = nb + row; if (gr >= n) gr = n - 1;
        za[i] = *reinterpret_cast<const uint4*>(Zb + (size_t)gr * 256 + col * 8);
    }
#pragma unroll
    for (int i = 0; i < 2; ++i) {
        int c = i * 256 + t;
        int row = c >> 3, col = c & 7;
        int gr = nb + row; if (gr >= n) gr = n - 1;
        zv[i] = *reinterpret_cast<const uint4*>(Vb + (size_t)gr * 64 + col * 8);
    }
    // phase 2: ds_write swizzled
#pragma unroll
    for (int i = 0; i < 8; ++i) {
        int c = i * 256 + t;
        int row = c >> 5, col = c & 31;
        *reinterpret_cast<uint4*>((char*)sA + row * 512 + ((col ^ (row & 7)) << 4)) = za[i];
    }
#pragma unroll
    for (int i = 0; i < 2; ++i) {
        int c = i * 256 + t;
        int row = c >> 3, col = c & 7;
        *reinterpret_cast<uint4*>((char*)sV + row * 128 + ((col ^ (row & 7)) << 4)) = zv[i];
    }
    __syncthreads();

    f32x4 acc[4][4];
#pragma unroll
    for (int mt = 0; mt < 4; ++mt)
#pragma unroll
        for (int nt = 0; nt < 4; ++nt)
            acc[mt][nt] = (f32x4){0.f, 0.f, 0.f, 0.f};

    const u16* bbase4[4];
#pragma unroll
    for (int nt = 0; nt < 4; ++nt)
        bbase4[nt] = Bt + (size_t)(w * 64 + nt * 16 + m16) * 320 + quad * 8;

    const u32 asw = (u32)(m16 & 7) << 4;

    for (int ks = 0; ks < 8; ++ks) {
        bf16x8 a[4], b[4];
#pragma unroll
        for (int mt = 0; mt < 4; ++mt)
            a[mt] = *reinterpret_cast<const bf16x8*>(
                (char*)sA + (u32)(mt * 16 + m16) * 512 +
                (((u32)(ks * 64 + quad * 16)) ^ asw));
#pragma unroll
        for (int nt = 0; nt < 4; ++nt)
            b[nt] = *reinterpret_cast<const bf16x8*>(bbase4[nt] + ks * 32);
#pragma unroll
        for (int mt = 0; mt < 4; ++mt)
#pragma unroll
            for (int nt = 0; nt < 4; ++nt)
                acc[mt][nt] = __builtin_amdgcn_mfma_f32_16x16x32_bf16(
                    a[mt], b[nt], acc[mt][nt], 0, 0, 0);
    }
#pragma unroll
    for (int ks = 8; ks < 10; ++ks) {
        bf16x8 a[4], b[4];
#pragma unroll
        for (int mt = 0; mt < 4; ++mt)
            a[mt] = *reinterpret_cast<const bf16x8*>(
                (char*)sV + (u32)(mt * 16 + m16) * 128 +
                (((u32)((ks - 8) * 64 + quad * 16)) ^ asw));
#pragma unroll
        for (int nt = 0; nt < 4; ++nt)
            b[nt] = *reinterpret_cast<const bf16x8*>(bbase4[nt] + ks * 32);
#pragma unroll
        for (int mt = 0; mt < 4; ++mt)
#pragma unroll
            for (int nt = 0; nt < 4; ++nt)
                acc[mt][nt] = __builtin_amdgcn_mfma_f32_16x16x32_bf16(
                    a[mt], b[nt], acc[mt][nt], 0, 0, 0);
    }

#pragma unroll
    for (int mt = 0; mt < 4; ++mt) {
#pragma unroll
        for (int r = 0; r < 4; ++r) {
            int row = nb + mt * 16 + quad * 4 + r;
            if (row < n) {
#pragma unroll
                for (int nt = 0; nt < 4; ++nt) {
                    int col = w * 64 + nt * 16 + m16;
                    out[(size_t)row * 256 + col] =
                        fmaxf(acc[mt][nt][r] - 0.05f, 0.f);
                }
            }
        }
    }
}

extern "C" void kernel_launch(void* const* d_in, const int* in_sizes, int n_in,
                              void* d_out, int out_size, void* d_ws, size_t ws_size,
                              hipStream_t stream) {
    const float* Z  = (const float*)d_in[0];
    const float* U  = (const float*)d_in[1];
    const float* Dm = (const float*)d_in[2];
    const float* hw = (const float*)d_in[3];
    const int*   ei = (const int*)d_in[4];
    const int n = in_sizes[0] / 256;       // 100000
    const int E = in_sizes[4] / 2;         // 1700000
    float* out = (float*)d_out;
    const int nbuck = (n + 255) >> 8;      // 391 (<= 512)

    // ws layout (~85 MB), lifetime-aliased:
    //   ZUb  bf16 n*64   (12.8 MB)  k_zumm -> k_agg
    //   Zb   bf16 n*256  (51.2 MB)  k_zumm -> k_out; OVERLAYS (dead after k_bucket):
    //        part int E (6.8 MB) | cnt2 int PB*nbuck | pre2 int PB*nbuck
    //   Vb   bf16 n*64   (12.8 MB)  k_agg -> k_out
    //   G, A fp32 64K ea; Bt bf16 256*320; U2t bf16 64*256
    //   esrc int E (6.8 MB)  k_bucket -> k_agg
    //   off, cnt int n; tot, bbase int nbuck
    char* wp = (char*)d_ws;
    u16* ZUb    = (u16*)wp;
    u16* Zb     = (u16*)(wp + (size_t)n * 128);
    int* part   = (int*)Zb;                 // aliases Zb (dead before k_zumm)
    int* cnt2   = part + E;
    int* pre2   = cnt2 + PB * nbuck;
    u16* Vb     = Zb + (size_t)n * 256;
    float* G    = (float*)(Vb + (size_t)n * 64);
    float* A    = G + 65536;
    u16* Bt     = (u16*)(A + 65536);
    u16* U2t    = Bt + 256 * 320;
    int* esrc   = (int*)(U2t + 64 * 256);
    int* off    = esrc + E;
    int* cnt    = off + n;
    int* tot    = cnt + n;
    int* bbase  = tot + nbuck;

    // prep (tiny)
    k_prep1<<<256, 256, 0, stream>>>(Dm, G);
    k_prep2<<<256, 256, 0, stream>>>(Dm, G, A);
    k_prep3<<<256, 256, 0, stream>>>(A, Bt);
    k_prep4<<<64, 256, 0, stream>>>(U, A, Bt);
    k_prep5<<<64, 256, 0, stream>>>(U, U2t);

    // CSR build (before k_zumm: part/cnt2/pre2 alias Zb)
    k_cnt1<<<PB, 256, 0, stream>>>(ei, cnt2, E, nbuck);
    k_cscan1<<<nbuck, 256, 0, stream>>>(cnt2, pre2, tot, nbuck);
    k_cscan2<<<1, 512, 0, stream>>>(tot, bbase, nbuck);
    k_place<<<PB, 256, 0, stream>>>(ei, pre2, bbase, part, E, nbuck);
    k_bucket<<<nbuck, 256, 0, stream>>>(part, tot, bbase, off, cnt, esrc, n);

    // main pipeline
    k_zumm<<<(n + 63) / 64, 256, 0, stream>>>(Z, U2t, ZUb, Zb, n);
    k_agg<<<(n + 3) / 4, 256, 0, stream>>>(ZUb, esrc, off, cnt, hw, Vb, n);
    k_out<<<(n + 63) / 64, 256, 0, stream>>>(Zb, Vb, Bt, out, n);
}